// Round 5
// baseline (552.203 us; speedup 1.0000x reference)
//
#include <hip/hip_runtime.h>
#include <cstdint>

typedef int i32x4 __attribute__((ext_vector_type(4)));
typedef int i32x16 __attribute__((ext_vector_type(16)));

#define M_DIM 8192
#define N_DIM 11008
#define K_DIM 4096
#define NTILES 64            // K-tiles of BK=64
#define DEPTH 4              // LDS ring depth

// ws layout (bytes)
#define WS_AMAX_OFF   0                      // 1024 floats
#define WS_WSUM_OFF   4096                   // 1024 doubles
#define WS_SCALES_OFF 12288                  // 4 floats
#define WS_QX_OFF     16384                  // 8192*4096 int8
#define WS_TW_OFF     (16384 + 33554432)     // 11008*4096 int8

__device__ __forceinline__ void gload_lds16(const void* g, void* l) {
  __builtin_amdgcn_global_load_lds(
      (const __attribute__((address_space(1))) unsigned int*)g,
      (__attribute__((address_space(3))) unsigned int*)l, 16, 0, 0);
}

// ---------------- reductions ----------------

__global__ void reduce_amax(const float* __restrict__ x, float* __restrict__ partial, int n4) {
  const float4* xv = (const float4*)x;
  float m = 0.f;
  for (long i = (long)blockIdx.x * blockDim.x + threadIdx.x; i < n4;
       i += (long)gridDim.x * blockDim.x) {
    float4 v = xv[i];
    m = fmaxf(m, fmaxf(fmaxf(fabsf(v.x), fabsf(v.y)), fmaxf(fabsf(v.z), fabsf(v.w))));
  }
  __shared__ float sm[256];
  sm[threadIdx.x] = m;
  __syncthreads();
  for (int s = 128; s > 0; s >>= 1) {
    if (threadIdx.x < s) sm[threadIdx.x] = fmaxf(sm[threadIdx.x], sm[threadIdx.x + s]);
    __syncthreads();
  }
  if (threadIdx.x == 0) partial[blockIdx.x] = sm[0];
}

__global__ void reduce_wsum(const float* __restrict__ w, double* __restrict__ partial, int n4) {
  const float4* wv = (const float4*)w;
  double acc = 0.0;
  for (long i = (long)blockIdx.x * blockDim.x + threadIdx.x; i < n4;
       i += (long)gridDim.x * blockDim.x) {
    float4 v = wv[i];
    acc += (double)fabsf(v.x) + (double)fabsf(v.y) + (double)fabsf(v.z) + (double)fabsf(v.w);
  }
  __shared__ double sd[256];
  sd[threadIdx.x] = acc;
  __syncthreads();
  for (int s = 128; s > 0; s >>= 1) {
    if (threadIdx.x < s) sd[threadIdx.x] += sd[threadIdx.x + s];
    __syncthreads();
  }
  if (threadIdx.x == 0) partial[blockIdx.x] = sd[0];
}

__global__ void finalize_scales(const float* __restrict__ amax_p,
                                const double* __restrict__ wsum_p,
                                float* __restrict__ scales) {
  __shared__ float sm[1024];
  __shared__ double sd[1024];
  const int t = threadIdx.x;
  sm[t] = amax_p[t];
  sd[t] = wsum_p[t];
  __syncthreads();
  for (int s = 512; s > 0; s >>= 1) {
    if (t < s) {
      sm[t] = fmaxf(sm[t], sm[t + s]);
      sd[t] += sd[t + s];
    }
    __syncthreads();
  }
  if (t == 0) {
    float act_scale = fmaxf(sm[0] / 127.0f, 1e-8f);
    float w_scale = (float)(sd[0] / (double)((long long)N_DIM * K_DIM)) + 1e-8f;
    scales[0] = act_scale;
    scales[1] = w_scale;
    scales[2] = act_scale * w_scale;
  }
}

// ---------------- quantize ----------------

__device__ __forceinline__ int quant_clip(float v, float s, float lim) {
  float r = rintf(v / s);                 // round-half-even, matches jnp.round
  r = fminf(fmaxf(r, -lim), lim);
  return (int)r;
}

__global__ void quant_x(const float* __restrict__ x, const float* __restrict__ scales,
                        int8_t* __restrict__ q) {
  const float s = scales[0];
  const long i = (long)blockIdx.x * blockDim.x + threadIdx.x;  // 16 elems/thread
  const float4* xv = (const float4*)x + (i << 2);
  i32x4 pk;
#pragma unroll
  for (int j = 0; j < 4; ++j) {
    float4 v = xv[j];
    int b0 = quant_clip(v.x, s, 127.f);
    int b1 = quant_clip(v.y, s, 127.f);
    int b2 = quant_clip(v.z, s, 127.f);
    int b3 = quant_clip(v.w, s, 127.f);
    pk[j] = (b0 & 255) | ((b1 & 255) << 8) | ((b2 & 255) << 16) | (b3 << 24);
  }
  *((i32x4*)q + i) = pk;
}

__global__ void tern_w(const float* __restrict__ w, const float* __restrict__ scales,
                       int8_t* __restrict__ q) {
  const float s = scales[1];
  const long i = (long)blockIdx.x * blockDim.x + threadIdx.x;
  const float4* wv = (const float4*)w + (i << 2);
  i32x4 pk;
#pragma unroll
  for (int j = 0; j < 4; ++j) {
    float4 v = wv[j];
    int b0 = quant_clip(v.x, s, 1.f);
    int b1 = quant_clip(v.y, s, 1.f);
    int b2 = quant_clip(v.z, s, 1.f);
    int b3 = quant_clip(v.w, s, 1.f);
    pk[j] = (b0 & 255) | ((b1 & 255) << 8) | ((b2 & 255) << 16) | (b3 << 24);
  }
  *((i32x4*)q + i) = pk;
}

// ---------------- int8 GEMM: 256x256 tile, BK=64, depth-4 ring pipeline ----------------
// 8 waves (2m x 4n), per-wave 128x64 output = acc[4][2] of 32x32 i32 tiles.
// LDS ring: 4 buffers x (A 16K + B 16K) = 128 KiB. Tile t staged at iter t-3.
// Iter t: vmcnt(8) [t's loads: issued 3 iters ago -> pre-satisfied]
//         lgkmcnt(0) [t-1 reads: already consumed by MFMAs -> free]
//         barrier    [t visible; t-1 reads done by ALL waves]
//         stage(t+3 -> buf[(t+3)&3] == t-1's buffer, now free)
//         12 ds_read_b128 (both k-slices) ; 16 MFMA (setprio)
// Tail: re-stage tile 63 into dead buffers (in-bounds, never read) to keep
// vmcnt counts uniform.
// LDS layout (BK=64): row-pairs per 128B line: byte(row,chunk) =
//   (row>>1)*128 + (row&1)*64 + (chunk ^ ((row>>1)&3))*16  — conflict-spread,
// linear on the gload_lds write side (global source carries the inverse perm).

__global__ __launch_bounds__(512, 2) void gemm_i8(const int8_t* __restrict__ qx,
                                                  const int8_t* __restrict__ tw,
                                                  const float* __restrict__ scales,
                                                  float* __restrict__ out) {
  __shared__ __align__(16) int8_t lds[DEPTH][32768];   // [d]: A 0..16K, B 16K..32K

  const int tid = threadIdx.x;
  const int l = tid & 63;
  const int w = tid >> 6;
  const int lane31 = l & 31;
  const int khalf = l >> 5;

  // ---- block -> tile mapping, 2D XCD chunk (bijective: 1376 = 8*172) ----
  const int bid = blockIdx.x;
  const int xcd = bid & 7;
  const int local = bid >> 3;               // 0..171
  const int ni = local >> 2;                // 0..42
  const int mi = (xcd << 2) + (local & 3);  // 0..31
  const long row0 = (long)mi << 8;
  const long col0 = (long)ni << 8;

  // ---- staging: wave w loads rows [32w,32w+32) of A and of B, 2 gloads each.
  // lane l of a gload: row = 2*(l>>3) + ((l>>2)&1), slot = l&3,
  // global chunk = slot ^ ((l>>3)&3)   (inverse of the read-side swizzle)
  const int srow = ((l >> 3) << 1) + ((l >> 2) & 1);
  const int schk = ((l & 3) ^ ((l >> 3) & 3)) << 4;
  const int8_t* pA = qx + (row0 + 32 * w + srow) * (long)K_DIM + schk;
  const int8_t* pB = tw + (col0 + 32 * w + srow) * (long)K_DIM + schk;
  const int ldsA = w << 11;                 // unit 2w at w*2048
  const int ldsB = 16384 + (w << 11);

  auto stage = [&](int d, int kt) {
    const long cb = (long)kt << 6;
    gload_lds16(pA + cb, lds[d] + ldsA);
    gload_lds16(pA + cb + 16 * (long)K_DIM, lds[d] + ldsA + 1024);
    gload_lds16(pB + cb, lds[d] + ldsB);
    gload_lds16(pB + cb + 16 * (long)K_DIM, lds[d] + ldsB + 1024);
  };

  // ---- read-side per-lane offsets ----
  const int rbl = ((lane31 >> 1) << 7) + ((lane31 & 1) << 6);
  const int x4 = (lane31 >> 1) & 3;
  int cOffR[4];
#pragma unroll
  for (int c = 0; c < 4; ++c) cOffR[c] = ((c ^ x4) << 4);
  const int aBase = ((w >> 2) << 13) + rbl;          // + mf*2048
  const int bBase = 16384 + ((w & 3) << 12) + rbl;   // + nf*2048

  i32x16 acc[4][2];
#pragma unroll
  for (int mf = 0; mf < 4; ++mf)
#pragma unroll
    for (int nf = 0; nf < 2; ++nf)
#pragma unroll
      for (int e = 0; e < 16; ++e) acc[mf][nf][e] = 0;

  // ---- prologue: tiles 0,1,2 in flight (12 gloads/wave) ----
  stage(0, 0);
  stage(1, 1);
  stage(2, 2);

#pragma unroll 4
  for (int t = 0; t < NTILES; ++t) {
    asm volatile("s_waitcnt vmcnt(8)" ::: "memory");   // tile t's own gloads done
    asm volatile("s_waitcnt lgkmcnt(0)" ::: "memory"); // own t-1 reads done (free)
    __builtin_amdgcn_s_barrier();                      // t visible; t-1 free
    asm volatile("" ::: "memory");

    const int kt3 = (t + 3 < NTILES) ? t + 3 : NTILES - 1;
    stage((t + 3) & 3, kt3);                           // overwrite t-1's buffer

    const int8_t* buf = lds[t & 3];

    // both k-slices' fragments (c = ks*2 + khalf)
    i32x4 a0[4], a1[4], b0[2], b1[2];
#pragma unroll
    for (int mf = 0; mf < 4; ++mf) {
      a0[mf] = *(const i32x4*)(buf + aBase + mf * 2048 + cOffR[khalf]);
      a1[mf] = *(const i32x4*)(buf + aBase + mf * 2048 + cOffR[2 + khalf]);
    }
#pragma unroll
    for (int nf = 0; nf < 2; ++nf) {
      b0[nf] = *(const i32x4*)(buf + bBase + nf * 2048 + cOffR[khalf]);
      b1[nf] = *(const i32x4*)(buf + bBase + nf * 2048 + cOffR[2 + khalf]);
    }

    __builtin_amdgcn_s_setprio(1);
#pragma unroll
    for (int mf = 0; mf < 4; ++mf) {
      acc[mf][0] = __builtin_amdgcn_mfma_i32_32x32x32_i8(a0[mf], b0[0], acc[mf][0], 0, 0, 0);
      acc[mf][1] = __builtin_amdgcn_mfma_i32_32x32x32_i8(a0[mf], b0[1], acc[mf][1], 0, 0, 0);
    }
#pragma unroll
    for (int mf = 0; mf < 4; ++mf) {
      acc[mf][0] = __builtin_amdgcn_mfma_i32_32x32x32_i8(a1[mf], b1[0], acc[mf][0], 0, 0, 0);
      acc[mf][1] = __builtin_amdgcn_mfma_i32_32x32x32_i8(a1[mf], b1[1], acc[mf][1], 0, 0, 0);
    }
    __builtin_amdgcn_s_setprio(0);
  }

  // ---- epilogue: C/D 32x32 layout: col=lane&31, row=(reg&3)+8*(reg>>2)+4*(lane>>5) ----
  const float osc = scales[2];
  const int rbase = khalf << 2;
#pragma unroll
  for (int mf = 0; mf < 4; ++mf)
#pragma unroll
    for (int nf = 0; nf < 2; ++nf)
#pragma unroll
      for (int reg = 0; reg < 16; ++reg) {
        int rr = (w >> 2) * 128 + mf * 32 + rbase + (reg & 3) + ((reg >> 2) << 3);
        int cc = (w & 3) * 64 + nf * 32 + lane31;
        out[(row0 + rr) * (long)N_DIM + (col0 + cc)] = (float)acc[mf][nf][reg] * osc;
      }
}

// ---------------- launch ----------------

extern "C" void kernel_launch(void* const* d_in, const int* in_sizes, int n_in,
                              void* d_out, int out_size, void* d_ws, size_t ws_size,
                              hipStream_t stream) {
  const float* x = (const float*)d_in[0];   // [4,2048,4096]
  const float* W = (const float*)d_in[1];   // [11008,4096]
  float* out = (float*)d_out;               // [4,2048,11008]

  char* ws = (char*)d_ws;
  float*  amax_p = (float*)(ws + WS_AMAX_OFF);
  double* wsum_p = (double*)(ws + WS_WSUM_OFF);
  float*  scales = (float*)(ws + WS_SCALES_OFF);
  int8_t* qx = (int8_t*)(ws + WS_QX_OFF);
  int8_t* tw = (int8_t*)(ws + WS_TW_OFF);

  reduce_amax<<<1024, 256, 0, stream>>>(x, amax_p, (M_DIM * (long)K_DIM) / 4);
  reduce_wsum<<<1024, 256, 0, stream>>>(W, wsum_p, (N_DIM * (long)K_DIM) / 4);
  finalize_scales<<<1, 1024, 0, stream>>>(amax_p, wsum_p, scales);
  quant_x<<<(M_DIM * (long)K_DIM) / 16 / 256, 256, 0, stream>>>(x, scales, qx);
  tern_w<<<(N_DIM * (long)K_DIM) / 16 / 256, 256, 0, stream>>>(W, scales, tw);

  const int grid = (M_DIM / 256) * (N_DIM / 256);   // 32*43 = 1376 = 8*172
  gemm_i8<<<grid, 512, 0, stream>>>(qx, tw, scales, out);
}